// Round 6
// baseline (819.187 us; speedup 1.0000x reference)
//
#include <hip/hip_runtime.h>
#include <hip/hip_cooperative_groups.h>
#include <math.h>

namespace cg = cooperative_groups;

#define N_NODES 50000
#define M_FEAT 128
#define E_EDGES 800000
#define B_PAIRS 100000
#define PRP 8              // stride for p/q/H/Hsum
#define PG 16              // stride for r/s

#define CH 4096                                  // edges per chunk (pass A)
#define NCHUNK ((E_EDGES + CH - 1) / CH)         // 196
#define NBUCKET ((N_NODES + 255) / 256)          // 196 coarse buckets (dst>>8)
#define HSZ (NBUCKET * NCHUNK)                   // 38416

#define TPB 256

// offsets into the small fused-weight buffer Wsm (256 floats)
#define OFF_WPP 0
#define OFF_WQQ 49
#define OFF_WR  98
#define OFF_WS  161
#define OFF_BP  224
#define OFF_BQ  231
#define OFF_BR  238
#define OFF_BS  247

struct MegaParams {
    const float* score;
    const int2*  edges;
    const int*   lab;
    const float* rp_w1, *rp_b1, *rp_w2, *rp_b2, *rp_w3, *rp_b3;
    const float* g_w1, *g_b1, *g_w2, *g_b2, *g_w3, *g_b3;
    float* out;
    float* p; float* q; float* H; float* Hs; float* r; float* s;
    float* Wbig; float* Wsm;
    int2* bucketed;
    int* srcSorted; int* histT; int* histTs; int* off;
};

// ====================================================================
// Cooperative mega-kernel: every phase is grid-stride -> correct for any
// grid >= 2 blocks. Grid size chosen by occupancy query on the host.
// ====================================================================

__global__ void __launch_bounds__(TPB) k_mega(MegaParams P) {
    cg::grid_group grid = cg::this_grid();
    __shared__ int shm[1024];
    const int tid   = threadIdx.x;
    const int bid   = blockIdx.x;
    const int G     = gridDim.x;
    const int gtid  = bid * TPB + tid;
    const int gsize = G * TPB;

    // ===== phase 0: coarse histogram (grid-stride chunks) + weight packing =====
    for (int c = bid; c < NCHUNK; c += G) {
        for (int i = tid; i < NBUCKET; i += TPB) shm[i] = 0;
        __syncthreads();
        int base = c * CH;
#pragma unroll
        for (int k = 0; k < CH / TPB; ++k) {
            int i = base + k * TPB + tid;
            if (i < E_EDGES) atomicAdd(&shm[P.edges[i].y >> 8], 1);
        }
        __syncthreads();
        for (int i = tid; i < NBUCKET; i += TPB) P.histT[i * NCHUNK + c] = shm[i];
        __syncthreads();
    }
    if (bid == G - 1) {
        // Wbig: 4096 copies
        for (int t = tid; t < 4096; t += TPB) {
            int m = t >> 5, o = t & 31;
            float v;
            if (o < 7)       v = P.rp_w1[m * 7 + o];
            else if (o < 14) v = P.rp_w1[(m + 128) * 7 + (o - 7)];
            else if (o < 23) v = P.g_w1[m * 9 + (o - 14)];
            else             v = P.g_w1[(m + 128) * 9 + (o - 23)];
            P.Wbig[m * 32 + o] = v;
        }
        // Wsm: 256 fused dot-products
        int t = tid;
        float acc = 0.f;
        if (t < 49) {
            int i = t / 7, j = t % 7;
            for (int m = 0; m < 128; ++m) acc = fmaf(P.rp_w3[i * 128 + m], P.rp_w1[m * 7 + j], acc);
        } else if (t < 98) {
            int u = t - 49; int i = u / 7, j = u % 7;
            for (int m = 0; m < 128; ++m) acc = fmaf(P.rp_w3[i * 128 + m], P.rp_w1[(m + 128) * 7 + j], acc);
        } else if (t < 161) {
            int u = t - 98; int i = u / 9, j = u % 9;
            for (int m = 0; m < 128; ++m) acc = fmaf(P.rp_w3[i * 128 + m], P.g_w1[m * 9 + j], acc);
        } else if (t < 224) {
            int u = t - 161; int i = u / 9, j = u % 9;
            for (int m = 0; m < 128; ++m) acc = fmaf(P.rp_w3[i * 128 + m], P.g_w1[(m + 128) * 9 + j], acc);
        } else if (t < 231) {
            int j = t - 224;
            for (int m = 0; m < 128; ++m) acc = fmaf(P.rp_b3[m], P.rp_w1[m * 7 + j], acc);
        } else if (t < 238) {
            int j = t - 231;
            for (int m = 0; m < 128; ++m) acc = fmaf(P.rp_b3[m], P.rp_w1[(m + 128) * 7 + j], acc);
        } else if (t < 247) {
            int j = t - 238;
            for (int m = 0; m < 128; ++m) acc = fmaf(P.rp_b3[m], P.g_w1[m * 9 + j], acc);
        } else {
            int j = t - 247;
            for (int m = 0; m < 128; ++m) acc = fmaf(P.rp_b3[m], P.g_w1[(m + 128) * 9 + j], acc);
        }
        P.Wsm[t] = acc;
    }
    grid.sync();

    // ===== phase 1: block 0 scans histT || other blocks project score =====
    if (bid == 0) {
        const int SEG = (HSZ + TPB - 1) / TPB;   // 151
        int lo = tid * SEG;
        int hi = lo + SEG; if (hi > HSZ) hi = HSZ;
        int sum = 0;
        for (int i = lo; i < hi; ++i) sum += P.histT[i];
        shm[tid] = sum;
        __syncthreads();
        for (int o = 1; o < TPB; o <<= 1) {
            int t2 = (tid >= o) ? shm[tid - o] : 0;
            __syncthreads();
            shm[tid] += t2;
            __syncthreads();
        }
        int run = shm[tid] - sum;                // exclusive prefix
        for (int i = lo; i < hi; ++i) {
            int v = P.histT[i];
            P.histTs[i] = run;
            run += v;
        }
    } else {
        int wv = (bid - 1) * 4 + (tid >> 6);
        int lane = tid & 63;
        int nw = (G - 1) * 4;
        int mg = lane >> 3, og = lane & 7;
        const float4* wb4 = reinterpret_cast<const float4*>(P.Wbig);
        float4 w[16];
#pragma unroll
        for (int i = 0; i < 16; ++i) w[i] = wb4[(mg * 16 + i) * 8 + og];
        for (int n = wv; n < N_NODES; n += nw) {
            const float4* srow = reinterpret_cast<const float4*>(P.score + n * M_FEAT + mg * 16);
            float a0 = 0.f, a1 = 0.f, a2 = 0.f, a3 = 0.f;
#pragma unroll
            for (int i = 0; i < 4; ++i) {
                float4 sv = srow[i];
                float se[4] = {sv.x, sv.y, sv.z, sv.w};
#pragma unroll
                for (int e = 0; e < 4; ++e) {
                    float4 ww = w[i * 4 + e];
                    a0 = fmaf(se[e], ww.x, a0);
                    a1 = fmaf(se[e], ww.y, a1);
                    a2 = fmaf(se[e], ww.z, a2);
                    a3 = fmaf(se[e], ww.w, a3);
                }
            }
#pragma unroll
            for (int off = 32; off >= 8; off >>= 1) {
                a0 += __shfl_down(a0, off);
                a1 += __shfl_down(a1, off);
                a2 += __shfl_down(a2, off);
                a3 += __shfl_down(a3, off);
            }
            if (mg == 0) {
                float outv[4] = {a0, a1, a2, a3};
#pragma unroll
                for (int jj = 0; jj < 4; ++jj) {
                    int o = og * 4 + jj;
                    float v = outv[jj];
                    if (o < 7)       P.p[n * PRP + o] = v;
                    else if (o < 14) P.q[n * PRP + (o - 7)] = v;
                    else if (o < 23) P.r[n * PG + (o - 14)] = v;
                    else             P.s[n * PG + (o - 23)] = v;
                }
            }
        }
    }
    grid.sync();

    // ===== phase 2: scatter edges into coarse buckets (grid-stride chunks) =====
    for (int c = bid; c < NCHUNK; c += G) {
        for (int i = tid; i < NBUCKET; i += TPB) shm[i] = P.histTs[i * NCHUNK + c];
        __syncthreads();
        int base = c * CH;
#pragma unroll
        for (int k = 0; k < CH / TPB; ++k) {
            int i = base + k * TPB + tid;
            if (i < E_EDGES) {
                int2 e = P.edges[i];
                int pos = atomicAdd(&shm[e.y >> 8], 1);
                P.bucketed[pos] = e;
            }
        }
        __syncthreads();
    }
    grid.sync();

    // ===== phase 3: per-bucket fine sort + CSR offsets (grid-stride buckets) =====
    for (int b = bid; b < NBUCKET; b += G) {
        int* cnt = shm;
        int* loc = shm + 256;
        int* cur = shm + 512;
        int* sh2 = shm + 768;
        int base0 = P.histTs[b * NCHUNK];
        int base1 = (b + 1 < NBUCKET) ? P.histTs[(b + 1) * NCHUNK] : E_EDGES;
        int nb = base1 - base0;
        cnt[tid] = 0;
        __syncthreads();
        for (int i = tid; i < nb; i += TPB)
            atomicAdd(&cnt[P.bucketed[base0 + i].y & 255], 1);
        __syncthreads();
        int v = cnt[tid];
        sh2[tid] = v;
        __syncthreads();
        for (int o = 1; o < TPB; o <<= 1) {
            int t2 = (tid >= o) ? sh2[tid - o] : 0;
            __syncthreads();
            sh2[tid] += t2;
            __syncthreads();
        }
        loc[tid] = sh2[tid] - v;
        cur[tid] = 0;
        __syncthreads();
        int d0 = b * 256;
        if (d0 + tid < N_NODES) P.off[d0 + tid] = base0 + loc[tid];
        if (b == 0 && tid == 0) P.off[N_NODES] = E_EDGES;
        for (int i = tid; i < nb; i += TPB) {
            int2 e = P.bucketed[base0 + i];
            int dl = e.y & 255;
            int pos = base0 + loc[dl] + atomicAdd(&cur[dl], 1);
            P.srcSorted[pos] = e.x;
        }
        __syncthreads();
    }
    grid.sync();

    // ===== 3 message-passing rounds in the projected space =====
    for (int round = 0; round < 3; ++round) {
        {
            float w2r[49], b1r[7], b2r[7];
#pragma unroll
            for (int i = 0; i < 49; ++i) w2r[i] = P.rp_w2[i];
#pragma unroll
            for (int k = 0; k < 7; ++k) { b1r[k] = P.rp_b1[k]; b2r[k] = P.rp_b2[k]; }
            for (int u = gtid; u < 4 * N_NODES; u += gsize) {
                int n = u >> 2, sub = u & 3;
                float qr[7], acc[7];
#pragma unroll
                for (int k = 0; k < 7; ++k) { qr[k] = P.q[n * PRP + k] + b1r[k]; acc[k] = 0.f; }
                int s0 = P.off[n], s1 = P.off[n + 1];
                for (int pos = s0 + sub; pos < s1; pos += 4) {
                    int src = P.srcSorted[pos];
                    float4 pa = *reinterpret_cast<const float4*>(P.p + src * PRP);
                    float4 pb = *reinterpret_cast<const float4*>(P.p + src * PRP + 4);
                    float h1[7];
                    h1[0] = fmaxf(pa.x + qr[0], 0.f);
                    h1[1] = fmaxf(pa.y + qr[1], 0.f);
                    h1[2] = fmaxf(pa.z + qr[2], 0.f);
                    h1[3] = fmaxf(pa.w + qr[3], 0.f);
                    h1[4] = fmaxf(pb.x + qr[4], 0.f);
                    h1[5] = fmaxf(pb.y + qr[5], 0.f);
                    h1[6] = fmaxf(pb.z + qr[6], 0.f);
#pragma unroll
                    for (int j = 0; j < 7; ++j) {
                        float vv = b2r[j];
#pragma unroll
                        for (int k = 0; k < 7; ++k) vv = fmaf(h1[k], w2r[k * 7 + j], vv);
                        acc[j] += fmaxf(vv, 0.f);
                    }
                }
#pragma unroll
                for (int j = 0; j < 7; ++j) {
                    acc[j] += __shfl_down(acc[j], 2);
                    acc[j] += __shfl_down(acc[j], 1);
                }
                if (sub == 0) {
#pragma unroll
                    for (int j = 0; j < 7; ++j) {
                        P.H[n * PRP + j] = acc[j];
                        if (round == 0) P.Hs[n * PRP + j] = acc[j];
                        else            P.Hs[n * PRP + j] += acc[j];
                    }
                }
            }
        }
        grid.sync();

        if (round < 2) {
            for (int n = gtid; n < N_NODES; n += gsize) {
                float h[7];
#pragma unroll
                for (int k = 0; k < 7; ++k) h[k] = P.H[n * PRP + k];
                float degf = (float)(P.off[n + 1] - P.off[n]);
#pragma unroll
                for (int j = 0; j < 7; ++j) {
                    float vp = degf * P.Wsm[OFF_BP + j];
                    float vq = degf * P.Wsm[OFF_BQ + j];
#pragma unroll
                    for (int i = 0; i < 7; ++i) {
                        vp = fmaf(h[i], P.Wsm[OFF_WPP + i * 7 + j], vp);
                        vq = fmaf(h[i], P.Wsm[OFF_WQQ + i * 7 + j], vq);
                    }
                    P.p[n * PRP + j] += vp;
                    P.q[n * PRP + j] += vq;
                }
            }
        } else {
            for (int n = gtid; n < N_NODES; n += gsize) {
                float h[7];
#pragma unroll
                for (int k = 0; k < 7; ++k) h[k] = P.Hs[n * PRP + k];
                float deg3 = 3.f * (float)(P.off[n + 1] - P.off[n]);
#pragma unroll
                for (int j = 0; j < 9; ++j) {
                    float vr = deg3 * P.Wsm[OFF_BR + j];
                    float vs = deg3 * P.Wsm[OFF_BS + j];
#pragma unroll
                    for (int i = 0; i < 7; ++i) {
                        vr = fmaf(h[i], P.Wsm[OFF_WR + i * 9 + j], vr);
                        vs = fmaf(h[i], P.Wsm[OFF_WS + i * 9 + j], vs);
                    }
                    P.r[n * PG + j] += vr;
                    P.s[n * PG + j] += vs;
                }
            }
        }
        grid.sync();
    }

    // ===== final pair scorer =====
    {
        for (int b = gtid; b < B_PAIRS; b += gsize) {
            int a0 = P.lab[2 * b];
            int a1 = P.lab[2 * b + 1];
            const float4* ra = reinterpret_cast<const float4*>(P.r + a0 * PG);
            const float4* sa = reinterpret_cast<const float4*>(P.s + a1 * PG);
            float4 r0 = ra[0], r1 = ra[1];
            float4 s0 = sa[0], s1 = sa[1];
            float rv[9] = {r0.x, r0.y, r0.z, r0.w, r1.x, r1.y, r1.z, r1.w, P.r[a0 * PG + 8]};
            float sv[9] = {s0.x, s0.y, s0.z, s0.w, s1.x, s1.y, s1.z, s1.w, P.s[a1 * PG + 8]};
            float g1[9];
#pragma unroll
            for (int k = 0; k < 9; ++k) g1[k] = fmaxf(rv[k] + sv[k] + P.g_b1[k], 0.f);
            float logit = P.g_b3[0];
#pragma unroll
            for (int j = 0; j < 9; ++j) {
                float vv = P.g_b2[j];
#pragma unroll
                for (int k = 0; k < 9; ++k) vv = fmaf(g1[k], P.g_w2[k * 9 + j], vv);
                logit = fmaf(fmaxf(vv, 0.f), P.g_w3[j], logit);
            }
            P.out[b] = 1.f / (1.f + expf(-logit));
        }
    }
}

// ====================================================================
// Fallback multi-kernel pipeline (round-4, proven at 124 us)
// ====================================================================

__global__ void k_histA(const int2* __restrict__ edges, int* __restrict__ histT) {
    __shared__ int cnt[NBUCKET];
    int c = blockIdx.x;
    int tid = threadIdx.x;
    if (tid < NBUCKET) cnt[tid] = 0;
    __syncthreads();
    int base = c * CH;
#pragma unroll
    for (int k = 0; k < CH / 256; ++k) {
        int i = base + k * 256 + tid;
        if (i < E_EDGES) atomicAdd(&cnt[edges[i].y >> 8], 1);
    }
    __syncthreads();
    if (tid < NBUCKET) histT[tid * NCHUNK + c] = cnt[tid];
}

__global__ void k_scan1(const int* __restrict__ in, int* __restrict__ part,
                        int* __restrict__ bsum, int n) {
    __shared__ int sh[256];
    int tid = threadIdx.x;
    int i = blockIdx.x * 256 + tid;
    int v = (i < n) ? in[i] : 0;
    sh[tid] = v;
    __syncthreads();
    for (int off = 1; off < 256; off <<= 1) {
        int t = (tid >= off) ? sh[tid - off] : 0;
        __syncthreads();
        sh[tid] += t;
        __syncthreads();
    }
    if (i < n) part[i] = sh[tid] - v;
    if (tid == 255) bsum[blockIdx.x] = sh[255];
}

__global__ void k_scan2(const int* __restrict__ bsum, int* __restrict__ boff, int nb) {
    __shared__ int sh[256];
    int tid = threadIdx.x;
    int v = (tid < nb) ? bsum[tid] : 0;
    sh[tid] = v;
    __syncthreads();
    for (int off = 1; off < 256; off <<= 1) {
        int t = (tid >= off) ? sh[tid - off] : 0;
        __syncthreads();
        sh[tid] += t;
        __syncthreads();
    }
    if (tid < nb) boff[tid] = sh[tid] - v;
}

__global__ void k_scan3(const int* __restrict__ part, const int* __restrict__ boff,
                        int* __restrict__ out, int n) {
    int i = blockIdx.x * blockDim.x + threadIdx.x;
    if (i < n) out[i] = part[i] + boff[i >> 8];
}

__global__ void k_scatterA(const int2* __restrict__ edges, const int* __restrict__ histTs,
                           int2* __restrict__ bucketed) {
    __shared__ int offl[NBUCKET];
    int c = blockIdx.x, tid = threadIdx.x;
    if (tid < NBUCKET) offl[tid] = histTs[tid * NCHUNK + c];
    __syncthreads();
    int base = c * CH;
#pragma unroll
    for (int k = 0; k < CH / 256; ++k) {
        int i = base + k * 256 + tid;
        if (i < E_EDGES) {
            int2 e = edges[i];
            int pos = atomicAdd(&offl[e.y >> 8], 1);
            bucketed[pos] = e;
        }
    }
}

__global__ void k_passB(const int2* __restrict__ bucketed, const int* __restrict__ histTs,
                        int* __restrict__ srcSorted, int* __restrict__ off) {
    __shared__ int cnt[256], loc[256], cur[256], sh[256];
    int b = blockIdx.x, tid = threadIdx.x;
    int base0 = histTs[b * NCHUNK];
    int base1 = (b + 1 < NBUCKET) ? histTs[(b + 1) * NCHUNK] : E_EDGES;
    int nb = base1 - base0;
    cnt[tid] = 0;
    __syncthreads();
    for (int i = tid; i < nb; i += 256)
        atomicAdd(&cnt[bucketed[base0 + i].y & 255], 1);
    __syncthreads();
    int v = cnt[tid];
    sh[tid] = v;
    __syncthreads();
    for (int o = 1; o < 256; o <<= 1) {
        int t = (tid >= o) ? sh[tid - o] : 0;
        __syncthreads();
        sh[tid] += t;
        __syncthreads();
    }
    loc[tid] = sh[tid] - v;
    cur[tid] = 0;
    __syncthreads();
    int d0 = b * 256;
    if (d0 + tid < N_NODES) off[d0 + tid] = base0 + loc[tid];
    if (b == 0 && tid == 0) off[N_NODES] = E_EDGES;
    for (int i = tid; i < nb; i += 256) {
        int2 e = bucketed[base0 + i];
        int dl = e.y & 255;
        int pos = base0 + loc[dl] + atomicAdd(&cur[dl], 1);
        srcSorted[pos] = e.x;
    }
}

__global__ void k_wpack(const float* __restrict__ rp_w1, const float* __restrict__ g_w1,
                        const float* __restrict__ w3, const float* __restrict__ b3,
                        float* __restrict__ Wbig, float* __restrict__ Wsm) {
    if (blockIdx.x < 16) {
        int t = blockIdx.x * 256 + threadIdx.x;
        int m = t >> 5, o = t & 31;
        float v;
        if (o < 7)       v = rp_w1[m * 7 + o];
        else if (o < 14) v = rp_w1[(m + 128) * 7 + (o - 7)];
        else if (o < 23) v = g_w1[m * 9 + (o - 14)];
        else             v = g_w1[(m + 128) * 9 + (o - 23)];
        Wbig[m * 32 + o] = v;
        return;
    }
    int t = threadIdx.x;
    float acc = 0.f;
    if (t < 49) {
        int i = t / 7, j = t % 7;
        for (int m = 0; m < 128; ++m) acc = fmaf(w3[i * 128 + m], rp_w1[m * 7 + j], acc);
    } else if (t < 98) {
        int u = t - 49; int i = u / 7, j = u % 7;
        for (int m = 0; m < 128; ++m) acc = fmaf(w3[i * 128 + m], rp_w1[(m + 128) * 7 + j], acc);
    } else if (t < 161) {
        int u = t - 98; int i = u / 9, j = u % 9;
        for (int m = 0; m < 128; ++m) acc = fmaf(w3[i * 128 + m], g_w1[m * 9 + j], acc);
    } else if (t < 224) {
        int u = t - 161; int i = u / 9, j = u % 9;
        for (int m = 0; m < 128; ++m) acc = fmaf(w3[i * 128 + m], g_w1[(m + 128) * 9 + j], acc);
    } else if (t < 231) {
        int j = t - 224;
        for (int m = 0; m < 128; ++m) acc = fmaf(b3[m], rp_w1[m * 7 + j], acc);
    } else if (t < 238) {
        int j = t - 231;
        for (int m = 0; m < 128; ++m) acc = fmaf(b3[m], rp_w1[(m + 128) * 7 + j], acc);
    } else if (t < 247) {
        int j = t - 238;
        for (int m = 0; m < 128; ++m) acc = fmaf(b3[m], g_w1[m * 9 + j], acc);
    } else {
        int j = t - 247;
        for (int m = 0; m < 128; ++m) acc = fmaf(b3[m], g_w1[(m + 128) * 9 + j], acc);
    }
    Wsm[t] = acc;
}

__global__ void __launch_bounds__(256) k_proj_fused(
        const float* __restrict__ score, const float* __restrict__ Wbig,
        float* __restrict__ p, float* __restrict__ q,
        float* __restrict__ r, float* __restrict__ s, int totalWaves) {
    int gtid = blockIdx.x * 256 + threadIdx.x;
    int wave = gtid >> 6, lane = gtid & 63;
    int mg = lane >> 3, og = lane & 7;
    const float4* wb4 = reinterpret_cast<const float4*>(Wbig);
    float4 w[16];
#pragma unroll
    for (int i = 0; i < 16; ++i) w[i] = wb4[(mg * 16 + i) * 8 + og];
    for (int n = wave; n < N_NODES; n += totalWaves) {
        const float4* srow = reinterpret_cast<const float4*>(score + n * M_FEAT + mg * 16);
        float a0 = 0.f, a1 = 0.f, a2 = 0.f, a3 = 0.f;
#pragma unroll
        for (int i = 0; i < 4; ++i) {
            float4 sv = srow[i];
            float se[4] = {sv.x, sv.y, sv.z, sv.w};
#pragma unroll
            for (int e = 0; e < 4; ++e) {
                float4 ww = w[i * 4 + e];
                a0 = fmaf(se[e], ww.x, a0);
                a1 = fmaf(se[e], ww.y, a1);
                a2 = fmaf(se[e], ww.z, a2);
                a3 = fmaf(se[e], ww.w, a3);
            }
        }
#pragma unroll
        for (int off = 32; off >= 8; off >>= 1) {
            a0 += __shfl_down(a0, off);
            a1 += __shfl_down(a1, off);
            a2 += __shfl_down(a2, off);
            a3 += __shfl_down(a3, off);
        }
        if (mg == 0) {
            float outv[4] = {a0, a1, a2, a3};
#pragma unroll
            for (int jj = 0; jj < 4; ++jj) {
                int o = og * 4 + jj;
                float v = outv[jj];
                if (o < 7)       p[n * PRP + o] = v;
                else if (o < 14) q[n * PRP + (o - 7)] = v;
                else if (o < 23) r[n * PG + (o - 14)] = v;
                else             s[n * PG + (o - 23)] = v;
            }
        }
    }
}

template <bool FIRST>
__global__ void k_edge_node(const int* __restrict__ srcSorted, const int* __restrict__ off,
                            const float* __restrict__ p, const float* __restrict__ q,
                            const float* __restrict__ w2, const float* __restrict__ b1,
                            const float* __restrict__ b2, float* __restrict__ H,
                            float* __restrict__ Hsum) {
    int gt = blockIdx.x * blockDim.x + threadIdx.x;
    int n = gt >> 3, sub = gt & 7;
    if (n >= N_NODES) return;
    float w2r[49], qr[7], b2r[7], acc[7];
#pragma unroll
    for (int i = 0; i < 49; ++i) w2r[i] = w2[i];
#pragma unroll
    for (int k = 0; k < 7; ++k) {
        qr[k] = q[n * PRP + k] + b1[k];
        b2r[k] = b2[k];
        acc[k] = 0.f;
    }
    int s0 = off[n], s1 = off[n + 1];
    for (int pos = s0 + sub; pos < s1; pos += 8) {
        int src = srcSorted[pos];
        float4 pa = *reinterpret_cast<const float4*>(p + src * PRP);
        float4 pb = *reinterpret_cast<const float4*>(p + src * PRP + 4);
        float h1[7];
        h1[0] = fmaxf(pa.x + qr[0], 0.f);
        h1[1] = fmaxf(pa.y + qr[1], 0.f);
        h1[2] = fmaxf(pa.z + qr[2], 0.f);
        h1[3] = fmaxf(pa.w + qr[3], 0.f);
        h1[4] = fmaxf(pb.x + qr[4], 0.f);
        h1[5] = fmaxf(pb.y + qr[5], 0.f);
        h1[6] = fmaxf(pb.z + qr[6], 0.f);
#pragma unroll
        for (int j = 0; j < 7; ++j) {
            float v = b2r[j];
#pragma unroll
            for (int k = 0; k < 7; ++k) v = fmaf(h1[k], w2r[k * 7 + j], v);
            acc[j] += fmaxf(v, 0.f);
        }
    }
#pragma unroll
    for (int j = 0; j < 7; ++j) {
        acc[j] += __shfl_down(acc[j], 4);
        acc[j] += __shfl_down(acc[j], 2);
        acc[j] += __shfl_down(acc[j], 1);
    }
    if (sub == 0) {
#pragma unroll
        for (int j = 0; j < 7; ++j) {
            H[n * PRP + j] = acc[j];
            if (FIRST) Hsum[n * PRP + j] = acc[j];
            else       Hsum[n * PRP + j] += acc[j];
        }
    }
}

__global__ void k_small_pq(float* __restrict__ p, float* __restrict__ q,
                           const float* __restrict__ H, const float* __restrict__ Wsm,
                           const int* __restrict__ off) {
    int n = blockIdx.x * blockDim.x + threadIdx.x;
    if (n >= N_NODES) return;
    float h[7];
#pragma unroll
    for (int k = 0; k < 7; ++k) h[k] = H[n * PRP + k];
    float degf = (float)(off[n + 1] - off[n]);
#pragma unroll
    for (int j = 0; j < 7; ++j) {
        float vp = degf * Wsm[OFF_BP + j];
        float vq = degf * Wsm[OFF_BQ + j];
#pragma unroll
        for (int i = 0; i < 7; ++i) {
            vp = fmaf(h[i], Wsm[OFF_WPP + i * 7 + j], vp);
            vq = fmaf(h[i], Wsm[OFF_WQQ + i * 7 + j], vq);
        }
        p[n * PRP + j] += vp;
        q[n * PRP + j] += vq;
    }
}

__global__ void k_small_rs(float* __restrict__ r, float* __restrict__ s,
                           const float* __restrict__ Hsum, const float* __restrict__ Wsm,
                           const int* __restrict__ off) {
    int n = blockIdx.x * blockDim.x + threadIdx.x;
    if (n >= N_NODES) return;
    float h[7];
#pragma unroll
    for (int k = 0; k < 7; ++k) h[k] = Hsum[n * PRP + k];
    float deg3 = 3.f * (float)(off[n + 1] - off[n]);
#pragma unroll
    for (int j = 0; j < 9; ++j) {
        float vr = deg3 * Wsm[OFF_BR + j];
        float vs = deg3 * Wsm[OFF_BS + j];
#pragma unroll
        for (int i = 0; i < 7; ++i) {
            vr = fmaf(h[i], Wsm[OFF_WR + i * 9 + j], vr);
            vs = fmaf(h[i], Wsm[OFF_WS + i * 9 + j], vs);
        }
        r[n * PG + j] += vr;
        s[n * PG + j] += vs;
    }
}

__global__ void k_pair(const int* __restrict__ lab, const float* __restrict__ r,
                       const float* __restrict__ s, const float* __restrict__ w2,
                       const float* __restrict__ b1, const float* __restrict__ b2,
                       const float* __restrict__ w3, const float* __restrict__ b3,
                       float* __restrict__ out) {
    int b = blockIdx.x * blockDim.x + threadIdx.x;
    if (b >= B_PAIRS) return;
    int a0 = lab[2 * b];
    int a1 = lab[2 * b + 1];
    const float4* ra = reinterpret_cast<const float4*>(r + a0 * PG);
    const float4* sa = reinterpret_cast<const float4*>(s + a1 * PG);
    float4 r0 = ra[0], r1 = ra[1];
    float4 s0 = sa[0], s1 = sa[1];
    float rv[9] = {r0.x, r0.y, r0.z, r0.w, r1.x, r1.y, r1.z, r1.w, r[a0 * PG + 8]};
    float sv[9] = {s0.x, s0.y, s0.z, s0.w, s1.x, s1.y, s1.z, s1.w, s[a1 * PG + 8]};
    float g1[9];
#pragma unroll
    for (int k = 0; k < 9; ++k) g1[k] = fmaxf(rv[k] + sv[k] + b1[k], 0.f);
    float logit = b3[0];
#pragma unroll
    for (int j = 0; j < 9; ++j) {
        float v = b2[j];
#pragma unroll
        for (int k = 0; k < 9; ++k) v = fmaf(g1[k], w2[k * 9 + j], v);
        logit = fmaf(fmaxf(v, 0.f), w3[j], logit);
    }
    out[b] = 1.f / (1.f + expf(-logit));
}

// ---------------- launch ----------------

extern "C" void kernel_launch(void* const* d_in, const int* in_sizes, int n_in,
                              void* d_out, int out_size, void* d_ws, size_t ws_size,
                              hipStream_t stream) {
    MegaParams P;
    P.score = (const float*)d_in[0];
    P.edges = (const int2*)d_in[1];
    P.lab   = (const int*)d_in[2];
    P.rp_w1 = (const float*)d_in[3];
    P.rp_b1 = (const float*)d_in[4];
    P.rp_w2 = (const float*)d_in[5];
    P.rp_b2 = (const float*)d_in[6];
    P.rp_w3 = (const float*)d_in[7];
    P.rp_b3 = (const float*)d_in[8];
    P.g_w1  = (const float*)d_in[9];
    P.g_b1  = (const float*)d_in[10];
    P.g_w2  = (const float*)d_in[11];
    P.g_b2  = (const float*)d_in[12];
    P.g_w3  = (const float*)d_in[13];
    P.g_b3  = (const float*)d_in[14];
    P.out   = (float*)d_out;

    float* ws = (float*)d_ws;
    P.p    = ws;                        // N*8
    P.q    = P.p + N_NODES * PRP;       // N*8
    P.H    = P.q + N_NODES * PRP;       // N*8
    P.Hs   = P.H + N_NODES * PRP;       // N*8
    P.r    = P.Hs + N_NODES * PRP;      // N*16
    P.s    = P.r + N_NODES * PG;        // N*16
    P.Wbig = P.s + N_NODES * PG;        // 4096
    P.Wsm  = P.Wbig + 4096;             // 256
    P.bucketed  = (int2*)(P.Wsm + 256);             // E int2 (8B-aligned)
    P.srcSorted = (int*)(P.bucketed + E_EDGES);     // E
    P.histT     = P.srcSorted + E_EDGES;            // HSZ
    P.histTs    = P.histT + HSZ;                    // HSZ
    P.off       = P.histTs + HSZ;                   // N+1

    // ---- size the cooperative grid from the runtime's occupancy query ----
    int dev = 0;
    (void)hipGetDevice(&dev);
    int numCU = 256;
    (void)hipDeviceGetAttribute(&numCU, hipDeviceAttributeMultiprocessorCount, dev);
    int occ = 0;
    hipError_t eo = hipOccupancyMaxActiveBlocksPerMultiprocessor(&occ, k_mega, TPB, 0);
    if (eo != hipSuccess || occ < 1) occ = 1;
    long long nblkLL = (long long)occ * (long long)numCU;
    int nblk = (nblkLL > 1024) ? 1024 : (int)nblkLL;
    if (nblk < 2) nblk = 2;

    void* args[] = {&P};
    hipError_t el = hipLaunchCooperativeKernel(reinterpret_cast<const void*>(&k_mega),
                                               dim3(nblk), dim3(TPB), args, 0, stream);
    if (el == hipSuccess) return;

    // ---- fallback: proven multi-kernel pipeline ----
    const int SCAN1_B = (HSZ + 255) / 256;
    k_histA<<<NCHUNK, 256, 0, stream>>>(P.edges, P.histT);
    // reuse bucketed area's tail for scan temporaries (sizes tiny, disjoint):
    {
        int* part = P.off + N_NODES + 1;        // HSZ ints
        int* bsum = part + HSZ;                 // 256
        int* boff = bsum + 256;                 // 256
        k_scan1<<<SCAN1_B, 256, 0, stream>>>(P.histT, part, bsum, HSZ);
        k_scan2<<<1, 256, 0, stream>>>(bsum, boff, SCAN1_B);
        k_scan3<<<SCAN1_B, 256, 0, stream>>>(part, boff, P.histTs, HSZ);
    }
    k_scatterA<<<NCHUNK, 256, 0, stream>>>(P.edges, P.histTs, P.bucketed);
    k_passB<<<NBUCKET, 256, 0, stream>>>(P.bucketed, P.histTs, P.srcSorted, P.off);
    k_wpack<<<17, 256, 0, stream>>>(P.rp_w1, P.g_w1, P.rp_w3, P.rp_b3, P.Wbig, P.Wsm);
    const int PROJ_BLOCKS = 1280;
    k_proj_fused<<<PROJ_BLOCKS, 256, 0, stream>>>(P.score, P.Wbig, P.p, P.q, P.r, P.s, PROJ_BLOCKS * 4);
    const int EG = (8 * N_NODES + 255) / 256;
    const int NG = (N_NODES + 255) / 256;
    k_edge_node<true><<<EG, 256, 0, stream>>>(P.srcSorted, P.off, P.p, P.q, P.rp_w2, P.rp_b1, P.rp_b2, P.H, P.Hs);
    k_small_pq<<<NG, 256, 0, stream>>>(P.p, P.q, P.H, P.Wsm, P.off);
    k_edge_node<false><<<EG, 256, 0, stream>>>(P.srcSorted, P.off, P.p, P.q, P.rp_w2, P.rp_b1, P.rp_b2, P.H, P.Hs);
    k_small_pq<<<NG, 256, 0, stream>>>(P.p, P.q, P.H, P.Wsm, P.off);
    k_edge_node<false><<<EG, 256, 0, stream>>>(P.srcSorted, P.off, P.p, P.q, P.rp_w2, P.rp_b1, P.rp_b2, P.H, P.Hs);
    k_small_rs<<<NG, 256, 0, stream>>>(P.r, P.s, P.Hs, P.Wsm, P.off);
    k_pair<<<(B_PAIRS + 255) / 256, 256, 0, stream>>>(P.lab, P.r, P.s, P.g_w2, P.g_b1, P.g_b2, P.g_w3, P.g_b3, P.out);
}

// Round 7
// 244.512 us; speedup vs baseline: 3.3503x; 3.3503x over previous
//
#include <hip/hip_runtime.h>
#include <math.h>

#define N_NODES 50000
#define M_FEAT 128
#define E_EDGES 800000
#define B_PAIRS 100000
#define PRP 8              // stride for p/q/Hs
#define PG 16              // stride for r/s

#define CH 4096                                  // edges per chunk (pass A)
#define NCHUNK ((E_EDGES + CH - 1) / CH)         // 196
#define NBUCKET ((N_NODES + 255) / 256)          // 196 coarse buckets (dst>>8)
#define HSZ (NBUCKET * NCHUNK)                   // 38416
#define EDGE_TPB 512

// offsets into the small fused-weight buffer Wsm (256 floats)
#define OFF_WPP 0
#define OFF_WQQ 49
#define OFF_WR  98
#define OFF_WS  161
#define OFF_BP  224
#define OFF_BQ  231
#define OFF_BR  238
#define OFF_BS  247

// ============ prep: coarse histogram (blocks 0..195) + weight packing ============

__global__ void k_prep(const int2* __restrict__ edges,
                       const float* __restrict__ rp_w1, const float* __restrict__ g_w1,
                       const float* __restrict__ w3, const float* __restrict__ b3,
                       int* __restrict__ histT, float* __restrict__ Wbig,
                       float* __restrict__ Wsm) {
    int bid = blockIdx.x, tid = threadIdx.x;
    if (bid < NCHUNK) {
        __shared__ int cnt[NBUCKET];
        if (tid < NBUCKET) cnt[tid] = 0;
        __syncthreads();
        int base = bid * CH;
#pragma unroll
        for (int k = 0; k < CH / 256; ++k) {
            int i = base + k * 256 + tid;
            if (i < E_EDGES) atomicAdd(&cnt[edges[i].y >> 8], 1);
        }
        __syncthreads();
        if (tid < NBUCKET) histT[tid * NCHUNK + bid] = cnt[tid];   // bucket-major
        return;
    }
    if (bid < NCHUNK + 16) {   // Wbig: 4096 entries
        int t = (bid - NCHUNK) * 256 + tid;
        int m = t >> 5, o = t & 31;
        float v;
        if (o < 7)       v = rp_w1[m * 7 + o];
        else if (o < 14) v = rp_w1[(m + 128) * 7 + (o - 7)];
        else if (o < 23) v = g_w1[m * 9 + (o - 14)];
        else             v = g_w1[(m + 128) * 9 + (o - 23)];
        Wbig[m * 32 + o] = v;
        return;
    }
    // Wsm: 256 fused dot-products
    int t = tid;
    float acc = 0.f;
    if (t < 49) {
        int i = t / 7, j = t % 7;
        for (int m = 0; m < 128; ++m) acc = fmaf(w3[i * 128 + m], rp_w1[m * 7 + j], acc);
    } else if (t < 98) {
        int u = t - 49; int i = u / 7, j = u % 7;
        for (int m = 0; m < 128; ++m) acc = fmaf(w3[i * 128 + m], rp_w1[(m + 128) * 7 + j], acc);
    } else if (t < 161) {
        int u = t - 98; int i = u / 9, j = u % 9;
        for (int m = 0; m < 128; ++m) acc = fmaf(w3[i * 128 + m], g_w1[m * 9 + j], acc);
    } else if (t < 224) {
        int u = t - 161; int i = u / 9, j = u % 9;
        for (int m = 0; m < 128; ++m) acc = fmaf(w3[i * 128 + m], g_w1[(m + 128) * 9 + j], acc);
    } else if (t < 231) {
        int j = t - 224;
        for (int m = 0; m < 128; ++m) acc = fmaf(b3[m], rp_w1[m * 7 + j], acc);
    } else if (t < 238) {
        int j = t - 231;
        for (int m = 0; m < 128; ++m) acc = fmaf(b3[m], rp_w1[(m + 128) * 7 + j], acc);
    } else if (t < 247) {
        int j = t - 238;
        for (int m = 0; m < 128; ++m) acc = fmaf(b3[m], g_w1[m * 9 + j], acc);
    } else {
        int j = t - 247;
        for (int m = 0; m < 128; ++m) acc = fmaf(b3[m], g_w1[(m + 128) * 9 + j], acc);
    }
    Wsm[t] = acc;
}

// ============ single-WG exclusive scan of histT (38416 entries) ============

__global__ void k_scanAll(const int* __restrict__ histT, int* __restrict__ histTs) {
    __shared__ int sh[1024];
    const int tid = threadIdx.x;
    const int SEG = (HSZ + 1023) / 1024;   // 38
    int lo = tid * SEG;
    int hi = lo + SEG; if (hi > HSZ) hi = HSZ;
    int sum = 0;
    for (int i = lo; i < hi; ++i) sum += histT[i];
    sh[tid] = sum;
    __syncthreads();
    for (int o = 1; o < 1024; o <<= 1) {
        int t2 = (tid >= o) ? sh[tid - o] : 0;
        __syncthreads();
        sh[tid] += t2;
        __syncthreads();
    }
    int run = sh[tid] - sum;               // exclusive prefix of this segment
    for (int i = lo; i < hi; ++i) {
        int v = histT[i];
        histTs[i] = run;
        run += v;
    }
}

// ============ scatter edges into coarse (256-dst) buckets ============

__global__ void k_scatterA(const int2* __restrict__ edges, const int* __restrict__ histTs,
                           int2* __restrict__ bucketed) {
    __shared__ int offl[NBUCKET];
    int c = blockIdx.x, tid = threadIdx.x;
    if (tid < NBUCKET) offl[tid] = histTs[tid * NCHUNK + c];
    __syncthreads();
    int base = c * CH;
#pragma unroll
    for (int k = 0; k < CH / 256; ++k) {
        int i = base + k * 256 + tid;
        if (i < E_EDGES) {
            int2 e = edges[i];
            int pos = atomicAdd(&offl[e.y >> 8], 1);
            bucketed[pos] = e;
        }
    }
}

// ============ fused projection: p,q,r,s = score0 @ Wbig ============

__global__ void __launch_bounds__(256) k_proj_fused(
        const float* __restrict__ score, const float* __restrict__ Wbig,
        float* __restrict__ p, float* __restrict__ q,
        float* __restrict__ r, float* __restrict__ s, int totalWaves) {
    int gtid = blockIdx.x * 256 + threadIdx.x;
    int wave = gtid >> 6, lane = gtid & 63;
    int mg = lane >> 3, og = lane & 7;
    const float4* wb4 = reinterpret_cast<const float4*>(Wbig);
    float4 w[16];
#pragma unroll
    for (int i = 0; i < 16; ++i) w[i] = wb4[(mg * 16 + i) * 8 + og];
    for (int n = wave; n < N_NODES; n += totalWaves) {
        const float4* srow = reinterpret_cast<const float4*>(score + n * M_FEAT + mg * 16);
        float a0 = 0.f, a1 = 0.f, a2 = 0.f, a3 = 0.f;
#pragma unroll
        for (int i = 0; i < 4; ++i) {
            float4 sv = srow[i];
            float se[4] = {sv.x, sv.y, sv.z, sv.w};
#pragma unroll
            for (int e = 0; e < 4; ++e) {
                float4 ww = w[i * 4 + e];
                a0 = fmaf(se[e], ww.x, a0);
                a1 = fmaf(se[e], ww.y, a1);
                a2 = fmaf(se[e], ww.z, a2);
                a3 = fmaf(se[e], ww.w, a3);
            }
        }
#pragma unroll
        for (int off = 32; off >= 8; off >>= 1) {
            a0 += __shfl_down(a0, off);
            a1 += __shfl_down(a1, off);
            a2 += __shfl_down(a2, off);
            a3 += __shfl_down(a3, off);
        }
        if (mg == 0) {
            float outv[4] = {a0, a1, a2, a3};
#pragma unroll
            for (int jj = 0; jj < 4; ++jj) {
                int o = og * 4 + jj;
                float v = outv[jj];
                if (o < 7)       p[n * PRP + o] = v;
                else if (o < 14) q[n * PRP + (o - 7)] = v;
                else if (o < 23) r[n * PG + (o - 14)] = v;
                else             s[n * PG + (o - 23)] = v;
            }
        }
    }
}

// ============ edge pass: one WG per bucket, LDS accumulation, fused pq update ============
// ROUND 0: gather pIn, write pOut = pIn+upd, q += upd, Hs = h, deg = count
// ROUND 1: gather pIn, write pOut = pIn+upd, q += upd, Hs += h
// ROUND 2: gather pIn only, Hs += h

template <int ROUND>
__global__ void __launch_bounds__(EDGE_TPB) k_edgeB(
        const int2* __restrict__ bucketed, const int* __restrict__ histTs,
        const float* __restrict__ pIn, float* __restrict__ pOut,
        float* __restrict__ q, float* __restrict__ Hs, int* __restrict__ deg,
        const float* __restrict__ w2, const float* __restrict__ b1,
        const float* __restrict__ b2, const float* __restrict__ Wsm) {
    __shared__ float qb[256 * 9];      // q[dst]+b1, stride 9 (bank-spread)
    __shared__ float Hacc[256 * 9];    // h2 accumulator, stride 9
    __shared__ float WsmL[256];
    __shared__ int degL[256];
    const int bid = blockIdx.x, tid = threadIdx.x;
    const int d0 = bid * 256;

    float b1r[7], b2r[7], w2r[49];
#pragma unroll
    for (int k = 0; k < 7; ++k) { b1r[k] = b1[k]; b2r[k] = b2[k]; }
#pragma unroll
    for (int i = 0; i < 49; ++i) w2r[i] = w2[i];
    if (tid < 256) WsmL[tid] = Wsm[tid];

    for (int i = tid; i < 256; i += EDGE_TPB) {
        int n = d0 + i;
        if (n < N_NODES) {
#pragma unroll
            for (int k = 0; k < 7; ++k) qb[i * 9 + k] = q[n * PRP + k] + b1r[k];
        }
#pragma unroll
        for (int k = 0; k < 7; ++k) Hacc[i * 9 + k] = 0.f;
        degL[i] = 0;
    }
    __syncthreads();

    const int base0 = histTs[bid * NCHUNK];
    const int base1 = (bid + 1 < NBUCKET) ? histTs[(bid + 1) * NCHUNK] : E_EDGES;

    int i = base0 + tid;
    bool valid = (i < base1);
    int2 e = {0, 0}; float4 pa = {}, pb = {};
    if (valid) {
        e = bucketed[i];
        pa = *reinterpret_cast<const float4*>(pIn + e.x * PRP);
        pb = *reinterpret_cast<const float4*>(pIn + e.x * PRP + 4);
    }
    while (valid) {
        int inext = i + EDGE_TPB;
        bool vnext = (inext < base1);
        int2 en = {0, 0}; float4 pan = {}, pbn = {};
        if (vnext) {                       // 1-deep prefetch of next edge's gather
            en = bucketed[inext];
            pan = *reinterpret_cast<const float4*>(pIn + en.x * PRP);
            pbn = *reinterpret_cast<const float4*>(pIn + en.x * PRP + 4);
        }
        int dl = e.y & 255;
        float h1[7];
        h1[0] = fmaxf(pa.x + qb[dl * 9 + 0], 0.f);
        h1[1] = fmaxf(pa.y + qb[dl * 9 + 1], 0.f);
        h1[2] = fmaxf(pa.z + qb[dl * 9 + 2], 0.f);
        h1[3] = fmaxf(pa.w + qb[dl * 9 + 3], 0.f);
        h1[4] = fmaxf(pb.x + qb[dl * 9 + 4], 0.f);
        h1[5] = fmaxf(pb.y + qb[dl * 9 + 5], 0.f);
        h1[6] = fmaxf(pb.z + qb[dl * 9 + 6], 0.f);
#pragma unroll
        for (int j = 0; j < 7; ++j) {
            float vv = b2r[j];
#pragma unroll
            for (int k = 0; k < 7; ++k) vv = fmaf(h1[k], w2r[k * 7 + j], vv);
            atomicAdd(&Hacc[dl * 9 + j], fmaxf(vv, 0.f));
        }
        if (ROUND == 0) atomicAdd(&degL[dl], 1);
        e = en; pa = pan; pb = pbn; i = inext; valid = vnext;
    }
    __syncthreads();

    // epilogue: this WG owns nodes [d0, d0+256) exclusively for q/Hs/deg/pOut
    for (int ii = tid; ii < 256; ii += EDGE_TPB) {
        int n = d0 + ii;
        if (n >= N_NODES) continue;
        float h[7];
#pragma unroll
        for (int k = 0; k < 7; ++k) h[k] = Hacc[ii * 9 + k];
        int dg;
        if (ROUND == 0) { dg = degL[ii]; deg[n] = dg; }
        else            dg = deg[n];
#pragma unroll
        for (int j = 0; j < 7; ++j) {
            if (ROUND == 0) Hs[n * PRP + j] = h[j];
            else            Hs[n * PRP + j] += h[j];
        }
        if (ROUND < 2) {
            float degf = (float)dg;
#pragma unroll
            for (int j = 0; j < 7; ++j) {
                float vp = degf * WsmL[OFF_BP + j];
                float vq = degf * WsmL[OFF_BQ + j];
#pragma unroll
                for (int i2 = 0; i2 < 7; ++i2) {
                    vp = fmaf(h[i2], WsmL[OFF_WPP + i2 * 7 + j], vp);
                    vq = fmaf(h[i2], WsmL[OFF_WQQ + i2 * 7 + j], vq);
                }
                pOut[n * PRP + j] = pIn[n * PRP + j] + vp;
                q[n * PRP + j] += vq;
            }
        }
    }
}

// ============ pair scorer with fused r/s finalization ============

__global__ void k_pair(const int* __restrict__ lab, const float* __restrict__ r,
                       const float* __restrict__ s, const float* __restrict__ Hs,
                       const int* __restrict__ deg, const float* __restrict__ Wsm,
                       const float* __restrict__ w2, const float* __restrict__ b1,
                       const float* __restrict__ b2, const float* __restrict__ w3,
                       const float* __restrict__ b3, float* __restrict__ out) {
    int b = blockIdx.x * blockDim.x + threadIdx.x;
    if (b >= B_PAIRS) return;
    int a0 = lab[2 * b];
    int a1 = lab[2 * b + 1];
    float h0[7], h1v[7];
#pragma unroll
    for (int k = 0; k < 7; ++k) { h0[k] = Hs[a0 * PRP + k]; h1v[k] = Hs[a1 * PRP + k]; }
    float d30 = 3.f * (float)deg[a0];
    float d31 = 3.f * (float)deg[a1];
    float g1[9];
#pragma unroll
    for (int j = 0; j < 9; ++j) {
        float vr = r[a0 * PG + j] + d30 * Wsm[OFF_BR + j];
        float vs = s[a1 * PG + j] + d31 * Wsm[OFF_BS + j];
#pragma unroll
        for (int i = 0; i < 7; ++i) {
            vr = fmaf(h0[i], Wsm[OFF_WR + i * 9 + j], vr);
            vs = fmaf(h1v[i], Wsm[OFF_WS + i * 9 + j], vs);
        }
        g1[j] = fmaxf(vr + vs + b1[j], 0.f);
    }
    float logit = b3[0];
#pragma unroll
    for (int j = 0; j < 9; ++j) {
        float v = b2[j];
#pragma unroll
        for (int k = 0; k < 9; ++k) v = fmaf(g1[k], w2[k * 9 + j], v);
        logit = fmaf(fmaxf(v, 0.f), w3[j], logit);
    }
    out[b] = 1.f / (1.f + expf(-logit));
}

// ---------------- launch: 8 dispatches ----------------

extern "C" void kernel_launch(void* const* d_in, const int* in_sizes, int n_in,
                              void* d_out, int out_size, void* d_ws, size_t ws_size,
                              hipStream_t stream) {
    const float* score = (const float*)d_in[0];
    const int2*  edges = (const int2*)d_in[1];
    const int*   lab   = (const int*)d_in[2];
    const float* rp_w1 = (const float*)d_in[3];
    const float* rp_b1 = (const float*)d_in[4];
    const float* rp_w2 = (const float*)d_in[5];
    const float* rp_b2 = (const float*)d_in[6];
    const float* rp_w3 = (const float*)d_in[7];
    const float* rp_b3 = (const float*)d_in[8];
    const float* g_w1  = (const float*)d_in[9];
    const float* g_b1  = (const float*)d_in[10];
    const float* g_w2  = (const float*)d_in[11];
    const float* g_b2  = (const float*)d_in[12];
    const float* g_w3  = (const float*)d_in[13];
    const float* g_b3  = (const float*)d_in[14];
    float* out = (float*)d_out;

    float* ws   = (float*)d_ws;
    float* pA   = ws;                      // N*8
    float* pB   = pA + N_NODES * PRP;      // N*8
    float* q    = pB + N_NODES * PRP;      // N*8
    float* Hs   = q + N_NODES * PRP;       // N*8
    float* r    = Hs + N_NODES * PRP;      // N*16
    float* s    = r + N_NODES * PG;        // N*16
    float* Wbig = s + N_NODES * PG;        // 4096
    float* Wsm  = Wbig + 4096;             // 256
    int2* bucketed = (int2*)(Wsm + 256);   // E int2 (8B-aligned offset: even float count)
    int* histT  = (int*)(bucketed + E_EDGES);  // HSZ
    int* histTs = histT + HSZ;                 // HSZ
    int* deg    = histTs + HSZ;                // N

    k_prep<<<NCHUNK + 17, 256, 0, stream>>>(edges, rp_w1, g_w1, rp_w3, rp_b3,
                                            histT, Wbig, Wsm);
    k_scanAll<<<1, 1024, 0, stream>>>(histT, histTs);
    k_scatterA<<<NCHUNK, 256, 0, stream>>>(edges, histTs, bucketed);
    const int PROJ_BLOCKS = 1280;
    k_proj_fused<<<PROJ_BLOCKS, 256, 0, stream>>>(score, Wbig, pA, q, r, s, PROJ_BLOCKS * 4);
    k_edgeB<0><<<NBUCKET, EDGE_TPB, 0, stream>>>(bucketed, histTs, pA, pB, q, Hs, deg,
                                                 rp_w2, rp_b1, rp_b2, Wsm);
    k_edgeB<1><<<NBUCKET, EDGE_TPB, 0, stream>>>(bucketed, histTs, pB, pA, q, Hs, deg,
                                                 rp_w2, rp_b1, rp_b2, Wsm);
    k_edgeB<2><<<NBUCKET, EDGE_TPB, 0, stream>>>(bucketed, histTs, pA, pB, q, Hs, deg,
                                                 rp_w2, rp_b1, rp_b2, Wsm);
    k_pair<<<(B_PAIRS + 255) / 256, 256, 0, stream>>>(lab, r, s, Hs, deg, Wsm,
                                                      g_w2, g_b1, g_b2, g_w3, g_b3, out);
}

// Round 8
// 194.534 us; speedup vs baseline: 4.2110x; 1.2569x over previous
//
#include <hip/hip_runtime.h>
#include <math.h>

#define N_NODES 50000
#define M_FEAT 128
#define E_EDGES 800000
#define B_PAIRS 100000
#define PRP 8              // stride for p/q/Hs
#define PG 16              // stride for r/s

#define CH 4096                                  // edges per chunk
#define NCHUNK ((E_EDGES + CH - 1) / CH)         // 196
#define NBUCKET ((N_NODES + 255) / 256)          // 196 coarse buckets (dst>>8)
#define HSZ (NBUCKET * NCHUNK)                   // 38416
#define EDGE_TPB 512
#define PROJ_BLOCKS 1100

// offsets into the small fused-weight buffer Wsm (256 floats)
#define OFF_WPP 0
#define OFF_WQQ 49
#define OFF_WR  98
#define OFF_WS  161
#define OFF_BP  224
#define OFF_BQ  231
#define OFF_BR  238
#define OFF_BS  247

// ============ prep: coarse histogram + weight packing ============

__global__ void __launch_bounds__(512) k_prep(
        const int2* __restrict__ edges,
        const float* __restrict__ rp_w1, const float* __restrict__ g_w1,
        const float* __restrict__ w3, const float* __restrict__ b3,
        int* __restrict__ histT, float* __restrict__ Wbig, float* __restrict__ Wsm) {
    int bid = blockIdx.x, tid = threadIdx.x;
    if (bid < NCHUNK) {
        __shared__ int cnt[NBUCKET];
        for (int i = tid; i < NBUCKET; i += 512) cnt[i] = 0;
        __syncthreads();
        int base = bid * CH;
#pragma unroll
        for (int k = 0; k < CH / 512; ++k) {
            int i = base + k * 512 + tid;
            if (i < E_EDGES) atomicAdd(&cnt[edges[i].y >> 8], 1);
        }
        __syncthreads();
        for (int i = tid; i < NBUCKET; i += 512) histT[i * NCHUNK + bid] = cnt[i];
        return;
    }
    if (bid < NCHUNK + 8) {   // Wbig: 4096 entries, 8 blocks x 512
        int t = (bid - NCHUNK) * 512 + tid;
        int m = t >> 5, o = t & 31;
        float v;
        if (o < 7)       v = rp_w1[m * 7 + o];
        else if (o < 14) v = rp_w1[(m + 128) * 7 + (o - 7)];
        else if (o < 23) v = g_w1[m * 9 + (o - 14)];
        else             v = g_w1[(m + 128) * 9 + (o - 23)];
        Wbig[m * 32 + o] = v;
        return;
    }
    // Wsm: 256 fused dot-products (threads 0..255)
    int t = tid;
    if (t >= 256) return;
    float acc = 0.f;
    if (t < 49) {
        int i = t / 7, j = t % 7;
        for (int m = 0; m < 128; ++m) acc = fmaf(w3[i * 128 + m], rp_w1[m * 7 + j], acc);
    } else if (t < 98) {
        int u = t - 49; int i = u / 7, j = u % 7;
        for (int m = 0; m < 128; ++m) acc = fmaf(w3[i * 128 + m], rp_w1[(m + 128) * 7 + j], acc);
    } else if (t < 161) {
        int u = t - 98; int i = u / 9, j = u % 9;
        for (int m = 0; m < 128; ++m) acc = fmaf(w3[i * 128 + m], g_w1[m * 9 + j], acc);
    } else if (t < 224) {
        int u = t - 161; int i = u / 9, j = u % 9;
        for (int m = 0; m < 128; ++m) acc = fmaf(w3[i * 128 + m], g_w1[(m + 128) * 9 + j], acc);
    } else if (t < 231) {
        int j = t - 224;
        for (int m = 0; m < 128; ++m) acc = fmaf(b3[m], rp_w1[m * 7 + j], acc);
    } else if (t < 238) {
        int j = t - 231;
        for (int m = 0; m < 128; ++m) acc = fmaf(b3[m], rp_w1[(m + 128) * 7 + j], acc);
    } else if (t < 247) {
        int j = t - 238;
        for (int m = 0; m < 128; ++m) acc = fmaf(b3[m], g_w1[m * 9 + j], acc);
    } else {
        int j = t - 247;
        for (int m = 0; m < 128; ++m) acc = fmaf(b3[m], g_w1[(m + 128) * 9 + j], acc);
    }
    Wsm[t] = acc;
}

// ============ per-bucket exclusive scan over chunks (196 WGs) ============

__global__ void k_scanB(const int* __restrict__ histT, int* __restrict__ histTs,
                        int* __restrict__ btot) {
    __shared__ int sh[256];
    int b = blockIdx.x, tid = threadIdx.x;
    int v = (tid < NCHUNK) ? histT[b * NCHUNK + tid] : 0;
    sh[tid] = v;
    __syncthreads();
    for (int o = 1; o < 256; o <<= 1) {
        int t2 = (tid >= o) ? sh[tid - o] : 0;
        __syncthreads();
        sh[tid] += t2;
        __syncthreads();
    }
    if (tid < NCHUNK) histTs[b * NCHUNK + tid] = sh[tid] - v;   // local exclusive
    if (tid == 255) btot[b] = sh[255];                           // bucket total
}

// ============ exclusive scan of bucket totals (1 WG) ============

__global__ void k_scanBase(const int* __restrict__ btot, int* __restrict__ bucketBase) {
    __shared__ int sh[256];
    int tid = threadIdx.x;
    int v = (tid < NBUCKET) ? btot[tid] : 0;
    sh[tid] = v;
    __syncthreads();
    for (int o = 1; o < 256; o <<= 1) {
        int t2 = (tid >= o) ? sh[tid - o] : 0;
        __syncthreads();
        sh[tid] += t2;
        __syncthreads();
    }
    if (tid < NBUCKET) bucketBase[tid] = sh[tid] - v;
    if (tid == 0) bucketBase[NBUCKET] = E_EDGES;
}

// ============ scatter (blocks 0..195) || projection (blocks 196..) ============

__global__ void __launch_bounds__(512) k_scatProj(
        const int2* __restrict__ edges, const int* __restrict__ histTs,
        const int* __restrict__ bucketBase, unsigned int* __restrict__ bucketed,
        const float* __restrict__ score, const float* __restrict__ Wbig,
        float* __restrict__ p, float* __restrict__ q,
        float* __restrict__ r, float* __restrict__ s) {
    __shared__ int offl[NBUCKET];
    const int bid = blockIdx.x, tid = threadIdx.x;
    if (bid < NCHUNK) {
        for (int i = tid; i < NBUCKET; i += 512)
            offl[i] = bucketBase[i] + histTs[i * NCHUNK + bid];
        __syncthreads();
        int base = bid * CH;
#pragma unroll
        for (int k = 0; k < CH / 512; ++k) {
            int i = base + k * 512 + tid;
            if (i < E_EDGES) {
                int2 e = edges[i];
                int pos = atomicAdd(&offl[e.y >> 8], 1);
                bucketed[pos] = ((unsigned int)(e.y & 255) << 16) | (unsigned int)e.x;
            }
        }
        return;
    }
    // ---- projection: p,q,r,s = score @ Wbig ----
    int wave = (bid - NCHUNK) * 8 + (tid >> 6);
    int lane = tid & 63;
    const int nw = PROJ_BLOCKS * 8;
    int mg = lane >> 3, og = lane & 7;
    const float4* wb4 = reinterpret_cast<const float4*>(Wbig);
    float4 w[16];
#pragma unroll
    for (int i = 0; i < 16; ++i) w[i] = wb4[(mg * 16 + i) * 8 + og];
    for (int n = wave; n < N_NODES; n += nw) {
        const float4* srow = reinterpret_cast<const float4*>(score + n * M_FEAT + mg * 16);
        float a0 = 0.f, a1 = 0.f, a2 = 0.f, a3 = 0.f;
#pragma unroll
        for (int i = 0; i < 4; ++i) {
            float4 sv = srow[i];
            float se[4] = {sv.x, sv.y, sv.z, sv.w};
#pragma unroll
            for (int e = 0; e < 4; ++e) {
                float4 ww = w[i * 4 + e];
                a0 = fmaf(se[e], ww.x, a0);
                a1 = fmaf(se[e], ww.y, a1);
                a2 = fmaf(se[e], ww.z, a2);
                a3 = fmaf(se[e], ww.w, a3);
            }
        }
#pragma unroll
        for (int off = 32; off >= 8; off >>= 1) {
            a0 += __shfl_down(a0, off);
            a1 += __shfl_down(a1, off);
            a2 += __shfl_down(a2, off);
            a3 += __shfl_down(a3, off);
        }
        if (mg == 0) {
            float outv[4] = {a0, a1, a2, a3};
#pragma unroll
            for (int jj = 0; jj < 4; ++jj) {
                int o = og * 4 + jj;
                float v = outv[jj];
                if (o < 7)       p[n * PRP + o] = v;
                else if (o < 14) q[n * PRP + (o - 7)] = v;
                else if (o < 23) r[n * PG + (o - 14)] = v;
                else             s[n * PG + (o - 23)] = v;
            }
        }
    }
}

// ============ edge pass: one WG per bucket, LDS accumulation, fused pq update ============

template <int ROUND>
__global__ void __launch_bounds__(EDGE_TPB) k_edgeB(
        const unsigned int* __restrict__ bucketed, const int* __restrict__ bucketBase,
        const float* __restrict__ pIn, float* __restrict__ pOut,
        float* __restrict__ q, float* __restrict__ Hs, int* __restrict__ deg,
        const float* __restrict__ w2, const float* __restrict__ b1,
        const float* __restrict__ b2, const float* __restrict__ Wsm) {
    __shared__ float qb[256 * 9];      // q[dst]+b1, stride 9 (bank-spread)
    __shared__ float Hacc[256 * 9];    // h2 accumulator, stride 9
    __shared__ float WsmL[256];
    __shared__ int degL[256];
    const int bid = blockIdx.x, tid = threadIdx.x;
    const int d0 = bid * 256;
    const int T = EDGE_TPB;

    float b1r[7], b2r[7], w2r[49];
#pragma unroll
    for (int k = 0; k < 7; ++k) { b1r[k] = b1[k]; b2r[k] = b2[k]; }
#pragma unroll
    for (int i = 0; i < 49; ++i) w2r[i] = w2[i];
    if (tid < 256) WsmL[tid] = Wsm[tid];

    for (int i = tid; i < 256; i += T) {
        int n = d0 + i;
        if (n < N_NODES) {
#pragma unroll
            for (int k = 0; k < 7; ++k) qb[i * 9 + k] = q[n * PRP + k] + b1r[k];
        }
#pragma unroll
        for (int k = 0; k < 7; ++k) Hacc[i * 9 + k] = 0.f;
        degL[i] = 0;
    }
    __syncthreads();

    const int base0 = bucketBase[bid];
    const int base1 = bucketBase[bid + 1];

    // 2-deep edge prefetch + 1-deep gather prefetch
    int i = base0 + tid;
    bool v0 = (i < base1), v1 = (i + T < base1);
    unsigned int ec = 0, en = 0;
    if (v0) ec = bucketed[i];
    if (v1) en = bucketed[i + T];
    float4 pa = {}, pb = {};
    if (v0) {
        int s0 = ec & 0xFFFF;
        pa = *reinterpret_cast<const float4*>(pIn + s0 * PRP);
        pb = *reinterpret_cast<const float4*>(pIn + s0 * PRP + 4);
    }
    while (v0) {
        bool v2 = (i + 2 * T < base1);
        unsigned int e2 = 0;
        if (v2) e2 = bucketed[i + 2 * T];
        float4 na = {}, nb = {};
        if (v1) {
            int s1 = en & 0xFFFF;
            na = *reinterpret_cast<const float4*>(pIn + s1 * PRP);
            nb = *reinterpret_cast<const float4*>(pIn + s1 * PRP + 4);
        }
        int dl = (int)(ec >> 16);
        float h1[7];
        h1[0] = fmaxf(pa.x + qb[dl * 9 + 0], 0.f);
        h1[1] = fmaxf(pa.y + qb[dl * 9 + 1], 0.f);
        h1[2] = fmaxf(pa.z + qb[dl * 9 + 2], 0.f);
        h1[3] = fmaxf(pa.w + qb[dl * 9 + 3], 0.f);
        h1[4] = fmaxf(pb.x + qb[dl * 9 + 4], 0.f);
        h1[5] = fmaxf(pb.y + qb[dl * 9 + 5], 0.f);
        h1[6] = fmaxf(pb.z + qb[dl * 9 + 6], 0.f);
#pragma unroll
        for (int j = 0; j < 7; ++j) {
            float vv = b2r[j];
#pragma unroll
            for (int k = 0; k < 7; ++k) vv = fmaf(h1[k], w2r[k * 7 + j], vv);
            atomicAdd(&Hacc[dl * 9 + j], fmaxf(vv, 0.f));
        }
        if (ROUND == 0) atomicAdd(&degL[dl], 1);
        ec = en; en = e2; pa = na; pb = nb; v0 = v1; v1 = v2; i += T;
    }
    __syncthreads();

    // epilogue: this WG owns nodes [d0, d0+256) exclusively for q/Hs/deg/pOut
    for (int ii = tid; ii < 256; ii += T) {
        int n = d0 + ii;
        if (n >= N_NODES) continue;
        float h[7];
#pragma unroll
        for (int k = 0; k < 7; ++k) h[k] = Hacc[ii * 9 + k];
        int dg;
        if (ROUND == 0) { dg = degL[ii]; deg[n] = dg; }
        else            dg = deg[n];
#pragma unroll
        for (int j = 0; j < 7; ++j) {
            if (ROUND == 0) Hs[n * PRP + j] = h[j];
            else            Hs[n * PRP + j] += h[j];
        }
        if (ROUND < 2) {
            float degf = (float)dg;
#pragma unroll
            for (int j = 0; j < 7; ++j) {
                float vp = degf * WsmL[OFF_BP + j];
                float vq = degf * WsmL[OFF_BQ + j];
#pragma unroll
                for (int i2 = 0; i2 < 7; ++i2) {
                    vp = fmaf(h[i2], WsmL[OFF_WPP + i2 * 7 + j], vp);
                    vq = fmaf(h[i2], WsmL[OFF_WQQ + i2 * 7 + j], vq);
                }
                pOut[n * PRP + j] = pIn[n * PRP + j] + vp;
                q[n * PRP + j] += vq;
            }
        }
    }
}

// ============ pair scorer with fused r/s finalization ============

__global__ void k_pair(const int* __restrict__ lab, const float* __restrict__ r,
                       const float* __restrict__ s, const float* __restrict__ Hs,
                       const int* __restrict__ deg, const float* __restrict__ Wsm,
                       const float* __restrict__ w2, const float* __restrict__ b1,
                       const float* __restrict__ b2, const float* __restrict__ w3,
                       const float* __restrict__ b3, float* __restrict__ out) {
    int b = blockIdx.x * blockDim.x + threadIdx.x;
    if (b >= B_PAIRS) return;
    int a0 = lab[2 * b];
    int a1 = lab[2 * b + 1];
    float h0[7], h1v[7];
#pragma unroll
    for (int k = 0; k < 7; ++k) { h0[k] = Hs[a0 * PRP + k]; h1v[k] = Hs[a1 * PRP + k]; }
    float d30 = 3.f * (float)deg[a0];
    float d31 = 3.f * (float)deg[a1];
    float g1[9];
#pragma unroll
    for (int j = 0; j < 9; ++j) {
        float vr = r[a0 * PG + j] + d30 * Wsm[OFF_BR + j];
        float vs = s[a1 * PG + j] + d31 * Wsm[OFF_BS + j];
#pragma unroll
        for (int i = 0; i < 7; ++i) {
            vr = fmaf(h0[i], Wsm[OFF_WR + i * 9 + j], vr);
            vs = fmaf(h1v[i], Wsm[OFF_WS + i * 9 + j], vs);
        }
        g1[j] = fmaxf(vr + vs + b1[j], 0.f);
    }
    float logit = b3[0];
#pragma unroll
    for (int j = 0; j < 9; ++j) {
        float v = b2[j];
#pragma unroll
        for (int k = 0; k < 9; ++k) v = fmaf(g1[k], w2[k * 9 + j], v);
        logit = fmaf(fmaxf(v, 0.f), w3[j], logit);
    }
    out[b] = 1.f / (1.f + expf(-logit));
}

// ---------------- launch: 8 dispatches ----------------

extern "C" void kernel_launch(void* const* d_in, const int* in_sizes, int n_in,
                              void* d_out, int out_size, void* d_ws, size_t ws_size,
                              hipStream_t stream) {
    const float* score = (const float*)d_in[0];
    const int2*  edges = (const int2*)d_in[1];
    const int*   lab   = (const int*)d_in[2];
    const float* rp_w1 = (const float*)d_in[3];
    const float* rp_b1 = (const float*)d_in[4];
    const float* rp_w2 = (const float*)d_in[5];
    const float* rp_b2 = (const float*)d_in[6];
    const float* rp_w3 = (const float*)d_in[7];
    const float* rp_b3 = (const float*)d_in[8];
    const float* g_w1  = (const float*)d_in[9];
    const float* g_b1  = (const float*)d_in[10];
    const float* g_w2  = (const float*)d_in[11];
    const float* g_b2  = (const float*)d_in[12];
    const float* g_w3  = (const float*)d_in[13];
    const float* g_b3  = (const float*)d_in[14];
    float* out = (float*)d_out;

    float* ws   = (float*)d_ws;
    float* pA   = ws;                      // N*8
    float* pB   = pA + N_NODES * PRP;      // N*8
    float* q    = pB + N_NODES * PRP;      // N*8
    float* Hs   = q + N_NODES * PRP;       // N*8
    float* r    = Hs + N_NODES * PRP;      // N*16
    float* s    = r + N_NODES * PG;        // N*16
    float* Wbig = s + N_NODES * PG;        // 4096
    float* Wsm  = Wbig + 4096;             // 256
    unsigned int* bucketed = (unsigned int*)(Wsm + 256);  // E uint32
    int* histT      = (int*)(bucketed + E_EDGES);  // HSZ
    int* histTs     = histT + HSZ;                 // HSZ
    int* btot       = histTs + HSZ;                // NBUCKET
    int* bucketBase = btot + NBUCKET;              // NBUCKET+1
    int* deg        = bucketBase + NBUCKET + 1;    // N

    k_prep<<<NCHUNK + 9, 512, 0, stream>>>(edges, rp_w1, g_w1, rp_w3, rp_b3,
                                           histT, Wbig, Wsm);
    k_scanB<<<NBUCKET, 256, 0, stream>>>(histT, histTs, btot);
    k_scanBase<<<1, 256, 0, stream>>>(btot, bucketBase);
    k_scatProj<<<NCHUNK + PROJ_BLOCKS, 512, 0, stream>>>(edges, histTs, bucketBase,
                                                         bucketed, score, Wbig, pA, q, r, s);
    k_edgeB<0><<<NBUCKET, EDGE_TPB, 0, stream>>>(bucketed, bucketBase, pA, pB, q, Hs, deg,
                                                 rp_w2, rp_b1, rp_b2, Wsm);
    k_edgeB<1><<<NBUCKET, EDGE_TPB, 0, stream>>>(bucketed, bucketBase, pB, pA, q, Hs, deg,
                                                 rp_w2, rp_b1, rp_b2, Wsm);
    k_edgeB<2><<<NBUCKET, EDGE_TPB, 0, stream>>>(bucketed, bucketBase, pA, pB, q, Hs, deg,
                                                 rp_w2, rp_b1, rp_b2, Wsm);
    k_pair<<<(B_PAIRS + 255) / 256, 256, 0, stream>>>(lab, r, s, Hs, deg, Wsm,
                                                      g_w2, g_b1, g_b2, g_w3, g_b3, out);
}